// Round 1
// baseline (278.437 us; speedup 1.0000x reference)
//
#include <hip/hip_runtime.h>

// ---------------- workspace layout (u32 indices) ----------------
#define WS_CANDCNT 0
#define WS_OVF     1
#define WS_B1      2
#define WS_K2      3
#define WS_K3      5
#define WS_PFX20   6
#define WS_FORCE   7
#define WS_THRESH  8
#define WS_HIST1   16
#define WS_HIST2   272           // 16 + 256
#define WS_HIST3   4368          // 272 + 4096
#define WS_CAND    8464          // 4368 + 4096; then candV[cap] floats, candI[cap] u32

// Monotone key: larger float (incl. negatives ordering) -> larger unsigned.
__device__ __forceinline__ unsigned fkey(float f) {
  unsigned x = __float_as_uint(f);
  return x ^ ((x & 0x80000000u) ? 0xFFFFFFFFu : 0x80000000u);
}
__device__ __forceinline__ float unkey(unsigned u) {
  unsigned x = u ^ ((u & 0x80000000u) ? 0x80000000u : 0xFFFFFFFFu);
  return __uint_as_float(x);
}

__global__ void zero_ws(unsigned* __restrict__ ws) {
  int i = blockIdx.x * blockDim.x + threadIdx.x;
  int stride = gridDim.x * blockDim.x;
  for (; i < WS_CAND; i += stride) ws[i] = 0u;
}

// Stage-1 histogram: top 8 bits of key, over all three inputs, float4 loads.
// 4-way replicated LDS histogram (adjacent words) to cut same-address atomic serialization.
__global__ void hist1_kernel(const float* __restrict__ e, const float* __restrict__ m,
                             const float* __restrict__ d, int n0v, int n1v, int nv,
                             unsigned* __restrict__ ws) {
  __shared__ unsigned h[1024];
  for (int i = threadIdx.x; i < 1024; i += blockDim.x) h[i] = 0u;
  __syncthreads();
  const int sub = threadIdx.x & 3;
  const int stride = gridDim.x * blockDim.x;
  for (int v = blockIdx.x * blockDim.x + threadIdx.x; v < nv; v += stride) {
    const float4* p; int off;
    if (v < n0v)            { p = (const float4*)e; off = v; }
    else if (v < n0v + n1v) { p = (const float4*)m; off = v - n0v; }
    else                    { p = (const float4*)d; off = v - n0v - n1v; }
    float4 f = p[off];
    atomicAdd(&h[((fkey(f.x) >> 24) << 2) | sub], 1u);
    atomicAdd(&h[((fkey(f.y) >> 24) << 2) | sub], 1u);
    atomicAdd(&h[((fkey(f.z) >> 24) << 2) | sub], 1u);
    atomicAdd(&h[((fkey(f.w) >> 24) << 2) | sub], 1u);
  }
  __syncthreads();
  for (int i = threadIdx.x; i < 256; i += blockDim.x) {
    unsigned c = h[i * 4] + h[i * 4 + 1] + h[i * 4 + 2] + h[i * 4 + 3];
    if (c) atomicAdd(&ws[WS_HIST1 + i], c);
  }
}

// Generic "find bucket containing k-th largest" over a histogram; single block of 256.
__global__ void select_kernel(unsigned* __restrict__ ws, const int* __restrict__ maxf,
                              long long n, int stage) {
  const int t = threadIdx.x;
  __shared__ unsigned part[256];
  const unsigned* hist;
  unsigned k;
  int nb;
  if (stage == 1) {
    hist = ws + WS_HIST1; nb = 256;
    long long kk = (long long)maxf[0] + 1;
    if (kk > n) {  // max_features >= n : thresh = 0.0f (reference semantics)
      if (t == 0) { ws[WS_FORCE] = 1u; ws[WS_B1] = 0x80u; ws[WS_K2] = 1u; }
      return;
    }
    k = (unsigned)kk;
  } else if (stage == 2) {
    if (ws[WS_FORCE]) { if (t == 0) { ws[WS_K3] = 1u; ws[WS_PFX20] = (0x80u << 12); } return; }
    hist = ws + WS_HIST2; nb = 4096; k = ws[WS_K2];
  } else {
    if (ws[WS_FORCE]) { if (t == 0) ws[WS_THRESH] = 0u; return; }  // bits of 0.0f
    hist = ws + WS_HIST3; nb = 4096; k = ws[WS_K3];
  }
  const int ch = nb >> 8;
  unsigned s = 0;
  for (int i = 0; i < ch; ++i) s += hist[t * ch + i];
  part[t] = s;
  __syncthreads();
  if (t == 0) {
    unsigned cum = 0; int b = -1; unsigned rem = 1;
    for (int c = 255; c >= 0; --c) {
      if (cum + part[c] >= k) {
        for (int bb = c * ch + ch - 1;; --bb) {
          unsigned hh = hist[bb];
          if (cum + hh >= k) { b = bb; rem = k - cum; break; }
          cum += hh;
        }
        break;
      }
      cum += part[c];
    }
    if (stage == 1)      { ws[WS_B1] = (unsigned)b; ws[WS_K2] = rem; ws[WS_FORCE] = 0u; }
    else if (stage == 2) { ws[WS_K3] = rem; ws[WS_PFX20] = (ws[WS_B1] << 12) | (unsigned)b; }
    else {
      unsigned u = (ws[WS_PFX20] << 12) | (unsigned)b;
      ws[WS_THRESH] = __float_as_uint(unkey(u));
    }
  }
}

// Fused pass: write provisional output + gather bucket-b1 candidates (value,index).
// One tile of 4096 elements (1024 float4) per block; one global atomic per block.
__global__ void __launch_bounds__(256) scatter_kernel(
    const float* __restrict__ e, const float* __restrict__ m, const float* __restrict__ d,
    float* __restrict__ out, int n0v, int n1v, int nv,
    unsigned* __restrict__ ws, unsigned cap) {
  const int t = threadIdx.x;
  const unsigned b1 = ws[WS_B1];
  float4 vals[4];
  int v4[4];
  unsigned c = 0;
  const int base_v = blockIdx.x * 1024;
  float4* out4 = (float4*)out;
#pragma unroll
  for (int j = 0; j < 4; ++j) {
    int v = base_v + j * 256 + t;
    v4[j] = v;
    if (v < nv) {
      const float4* p; int off;
      if (v < n0v)            { p = (const float4*)e; off = v; }
      else if (v < n0v + n1v) { p = (const float4*)m; off = v - n0v; }
      else                    { p = (const float4*)d; off = v - n0v - n1v; }
      float4 f = p[off];
      vals[j] = f;
      unsigned bx = fkey(f.x) >> 24, by = fkey(f.y) >> 24;
      unsigned bz = fkey(f.z) >> 24, bw = fkey(f.w) >> 24;
      float4 o;
      o.x = (bx >= b1) ? f.x : 0.0f;
      o.y = (by >= b1) ? f.y : 0.0f;
      o.z = (bz >= b1) ? f.z : 0.0f;
      o.w = (bw >= b1) ? f.w : 0.0f;
      out4[v] = o;
      c += (bx == b1) + (by == b1) + (bz == b1) + (bw == b1);
    }
  }
  // block-wide exclusive prefix of candidate counts
  __shared__ unsigned sc[256];
  __shared__ unsigned baseSh;
  sc[t] = c;
  __syncthreads();
  for (int s1 = 1; s1 < 256; s1 <<= 1) {
    unsigned vv = (t >= s1) ? sc[t - s1] : 0u;
    __syncthreads();
    sc[t] += vv;
    __syncthreads();
  }
  const unsigned total = sc[255];
  const unsigned excl = sc[t] - c;
  if (t == 0) {
    unsigned base = total ? atomicAdd(&ws[WS_CANDCNT], total) : 0u;
    baseSh = base;
    if (base + total > cap) atomicOr(&ws[WS_OVF], 1u);
  }
  __syncthreads();
  if (c) {
    unsigned slot = baseSh + excl;
    float* candV = (float*)(ws + WS_CAND);
    unsigned* candI = ws + WS_CAND + cap;
#pragma unroll
    for (int j = 0; j < 4; ++j) {
      int v = v4[j];
      if (v >= nv) continue;
      float ff[4] = {vals[j].x, vals[j].y, vals[j].z, vals[j].w};
#pragma unroll
      for (int cc = 0; cc < 4; ++cc) {
        if ((fkey(ff[cc]) >> 24) == b1) {
          if (slot < cap) { candV[slot] = ff[cc]; candI[slot] = (unsigned)v * 4u + cc; }
          slot++;
        }
      }
    }
  }
}

// Stage-2/3 histograms over gathered candidates (fast) or full rescan (overflow fallback).
__global__ void cand_hist_kernel(const float* __restrict__ e, const float* __restrict__ m,
                                 const float* __restrict__ d, long long n0, long long n01,
                                 long long n, unsigned* __restrict__ ws, unsigned cap, int stage) {
  __shared__ unsigned h[4096];
  for (int i = threadIdx.x; i < 4096; i += blockDim.x) h[i] = 0u;
  __syncthreads();
  long long gtid = (long long)blockIdx.x * blockDim.x + threadIdx.x;
  long long stride = (long long)gridDim.x * blockDim.x;
  if (!ws[WS_OVF]) {
    const unsigned cnt = ws[WS_CANDCNT];
    const float* candV = (const float*)(ws + WS_CAND);
    if (stage == 2) {
      for (long long i = gtid; i < cnt; i += stride) {
        unsigned u = fkey(candV[i]);
        atomicAdd(&h[(u >> 12) & 0xFFFu], 1u);
      }
    } else {
      const unsigned pfx = ws[WS_PFX20];
      for (long long i = gtid; i < cnt; i += stride) {
        unsigned u = fkey(candV[i]);
        if ((u >> 12) == pfx) atomicAdd(&h[u & 0xFFFu], 1u);
      }
    }
  } else {
    const unsigned b1 = ws[WS_B1];
    const unsigned pfx = ws[WS_PFX20];
    for (long long i = gtid; i < n; i += stride) {
      const float* p; long long off;
      if (i < n0)       { p = e; off = i; }
      else if (i < n01) { p = m; off = i - n0; }
      else              { p = d; off = i - n01; }
      unsigned u = fkey(p[off]);
      if (stage == 2) { if ((u >> 24) == b1) atomicAdd(&h[(u >> 12) & 0xFFFu], 1u); }
      else            { if ((u >> 12) == pfx) atomicAdd(&h[u & 0xFFFu], 1u); }
    }
  }
  __syncthreads();
  unsigned* gh = ws + (stage == 2 ? WS_HIST2 : WS_HIST3);
  for (int i = threadIdx.x; i < 4096; i += blockDim.x) {
    unsigned cc = h[i];
    if (cc) atomicAdd(&gh[i], cc);
  }
}

// Zero the provisionally-kept candidates that are below the exact threshold.
__global__ void fixup_kernel(const float* __restrict__ e, const float* __restrict__ m,
                             const float* __restrict__ d, float* __restrict__ out,
                             long long n0, long long n01, long long n,
                             unsigned* __restrict__ ws, unsigned cap) {
  const float thresh = __uint_as_float(ws[WS_THRESH]);
  long long gtid = (long long)blockIdx.x * blockDim.x + threadIdx.x;
  long long stride = (long long)gridDim.x * blockDim.x;
  if (!ws[WS_OVF]) {
    const unsigned cnt = ws[WS_CANDCNT];
    const float* candV = (const float*)(ws + WS_CAND);
    const unsigned* candI = ws + WS_CAND + cap;
    for (long long i = gtid; i < cnt; i += stride) {
      float f = candV[i];
      if (f < thresh) out[candI[i]] = 0.0f;
    }
  } else {
    const unsigned b1 = ws[WS_B1];
    for (long long i = gtid; i < n; i += stride) {
      const float* p; long long off;
      if (i < n0)       { p = e; off = i; }
      else if (i < n01) { p = m; off = i - n0; }
      else              { p = d; off = i - n01; }
      float f = p[off];
      if ((fkey(f) >> 24) == b1 && f < thresh) out[i] = 0.0f;
    }
  }
}

extern "C" void kernel_launch(void* const* d_in, const int* in_sizes, int n_in,
                              void* d_out, int out_size, void* d_ws, size_t ws_size,
                              hipStream_t stream) {
  const float* e = (const float*)d_in[0];
  const float* m = (const float*)d_in[1];
  const float* d = (const float*)d_in[2];
  const int* maxf = (const int*)d_in[3];
  float* out = (float*)d_out;
  unsigned* ws = (unsigned*)d_ws;

  const long long n0 = in_sizes[0], n1 = in_sizes[1], n2 = in_sizes[2];
  const long long n = n0 + n1 + n2;
  const int n0v = (int)(n0 / 4), n1v = (int)(n1 / 4), nv = (int)(n / 4);

  long long capll = ((long long)(ws_size / 4) - WS_CAND) / 2;
  if (capll < 0) capll = 0;
  if (capll > n) capll = n;
  const unsigned cap = (unsigned)capll;

  zero_ws<<<8, 256, 0, stream>>>(ws);
  hist1_kernel<<<1024, 256, 0, stream>>>(e, m, d, n0v, n1v, nv, ws);
  select_kernel<<<1, 256, 0, stream>>>(ws, maxf, n, 1);
  const int nblocks = (nv + 1023) / 1024;
  scatter_kernel<<<nblocks, 256, 0, stream>>>(e, m, d, out, n0v, n1v, nv, ws, cap);
  cand_hist_kernel<<<64, 256, 0, stream>>>(e, m, d, n0, n0 + n1, n, ws, cap, 2);
  select_kernel<<<1, 256, 0, stream>>>(ws, maxf, n, 2);
  cand_hist_kernel<<<64, 256, 0, stream>>>(e, m, d, n0, n0 + n1, n, ws, cap, 3);
  select_kernel<<<1, 256, 0, stream>>>(ws, maxf, n, 3);
  fixup_kernel<<<512, 256, 0, stream>>>(e, m, d, out, n0, n0 + n1, n, ws, cap);
}

// Round 3
// 269.933 us; speedup vs baseline: 1.0315x; 1.0315x over previous
//
#include <hip/hip_runtime.h>

typedef float nfloat4 __attribute__((ext_vector_type(4)));  // native vec for NT stores

// ---------------- workspace layout (u32 indices) ----------------
#define WS_CANDCNT 0
#define WS_OVF     1
#define WS_B1      2
#define WS_K2      3
#define WS_K3      5
#define WS_PFX20   6
#define WS_FORCE   7
#define WS_THRESH  8
#define WS_HIST1   16
#define WS_HIST2   272           // 16 + 256
#define WS_HIST3   4368          // 272 + 4096
#define WS_CAND    8464          // 4368 + 4096; then candV[cap] floats, candI[cap] u32

// Monotone key: larger float (incl. negatives ordering) -> larger unsigned.
__device__ __forceinline__ unsigned fkey(float f) {
  unsigned x = __float_as_uint(f);
  return x ^ ((x & 0x80000000u) ? 0xFFFFFFFFu : 0x80000000u);
}
__device__ __forceinline__ float unkey(unsigned u) {
  unsigned x = u ^ ((u & 0x80000000u) ? 0x80000000u : 0xFFFFFFFFu);
  return __uint_as_float(x);
}

__global__ void zero_ws(unsigned* __restrict__ ws) {
  int i = blockIdx.x * blockDim.x + threadIdx.x;
  if (i < WS_CAND) ws[i] = 0u;
}

// Stage-1 histogram: top 8 bits of key. 32-way lane-replicated LDS histogram:
// h[bucket*32 + (lane&31)] -> within a half-wave no two lanes ever hit the same
// address, and bank == lane&31 (conflict-free). Cross-wave collisions are rare.
__global__ void __launch_bounds__(256) hist1_kernel(
    const float* __restrict__ e, const float* __restrict__ m,
    const float* __restrict__ d, int n0v, int n1v, int n2v,
    unsigned* __restrict__ ws) {
  __shared__ unsigned h[256 * 32];
  for (int i = threadIdx.x; i < 256 * 32; i += blockDim.x) h[i] = 0u;
  __syncthreads();
  const unsigned sub = threadIdx.x & 31u;
  const int gid = blockIdx.x * blockDim.x + threadIdx.x;
  const int gstride = gridDim.x * blockDim.x;
  const float4* e4 = (const float4*)e;
  const float4* m4 = (const float4*)m;
  const float4* d4 = (const float4*)d;
  for (int v = gid; v < n0v; v += gstride) {
    float4 f = e4[v];
    atomicAdd(&h[((fkey(f.x) >> 24) << 5) | sub], 1u);
    atomicAdd(&h[((fkey(f.y) >> 24) << 5) | sub], 1u);
    atomicAdd(&h[((fkey(f.z) >> 24) << 5) | sub], 1u);
    atomicAdd(&h[((fkey(f.w) >> 24) << 5) | sub], 1u);
  }
  for (int v = gid; v < n1v; v += gstride) {
    float4 f = m4[v];
    atomicAdd(&h[((fkey(f.x) >> 24) << 5) | sub], 1u);
    atomicAdd(&h[((fkey(f.y) >> 24) << 5) | sub], 1u);
    atomicAdd(&h[((fkey(f.z) >> 24) << 5) | sub], 1u);
    atomicAdd(&h[((fkey(f.w) >> 24) << 5) | sub], 1u);
  }
  for (int v = gid; v < n2v; v += gstride) {
    float4 f = d4[v];
    atomicAdd(&h[((fkey(f.x) >> 24) << 5) | sub], 1u);
    atomicAdd(&h[((fkey(f.y) >> 24) << 5) | sub], 1u);
    atomicAdd(&h[((fkey(f.z) >> 24) << 5) | sub], 1u);
    atomicAdd(&h[((fkey(f.w) >> 24) << 5) | sub], 1u);
  }
  __syncthreads();
  // one bucket per thread; staggered copy reads to spread banks
  const int t = threadIdx.x;
  unsigned s = 0;
#pragma unroll
  for (int j = 0; j < 32; ++j) s += h[(t << 5) + ((t + j) & 31)];
  if (s) atomicAdd(&ws[WS_HIST1 + t], s);
}

// Generic "find bucket containing k-th largest" over a histogram; single block of 256.
__global__ void select_kernel(unsigned* __restrict__ ws, const int* __restrict__ maxf,
                              long long n, int stage) {
  const int t = threadIdx.x;
  __shared__ unsigned part[256];
  const unsigned* hist;
  unsigned k;
  int nb;
  if (stage == 1) {
    hist = ws + WS_HIST1; nb = 256;
    long long kk = (long long)maxf[0] + 1;
    if (kk > n) {  // max_features >= n : thresh = 0.0f (reference semantics)
      if (t == 0) { ws[WS_FORCE] = 1u; ws[WS_B1] = 0x80u; ws[WS_K2] = 1u; }
      return;
    }
    k = (unsigned)kk;
  } else if (stage == 2) {
    if (ws[WS_FORCE]) { if (t == 0) { ws[WS_K3] = 1u; ws[WS_PFX20] = (0x80u << 12); } return; }
    hist = ws + WS_HIST2; nb = 4096; k = ws[WS_K2];
  } else {
    if (ws[WS_FORCE]) { if (t == 0) ws[WS_THRESH] = 0u; return; }  // bits of 0.0f
    hist = ws + WS_HIST3; nb = 4096; k = ws[WS_K3];
  }
  const int ch = nb >> 8;
  unsigned s = 0;
  for (int i = 0; i < ch; ++i) s += hist[t * ch + i];
  part[t] = s;
  __syncthreads();
  if (t == 0) {
    unsigned cum = 0; int b = -1; unsigned rem = 1;
    for (int c = 255; c >= 0; --c) {
      if (cum + part[c] >= k) {
        for (int bb = c * ch + ch - 1;; --bb) {
          unsigned hh = hist[bb];
          if (cum + hh >= k) { b = bb; rem = k - cum; break; }
          cum += hh;
        }
        break;
      }
      cum += part[c];
    }
    if (stage == 1)      { ws[WS_B1] = (unsigned)b; ws[WS_K2] = rem; ws[WS_FORCE] = 0u; }
    else if (stage == 2) { ws[WS_K3] = rem; ws[WS_PFX20] = (ws[WS_B1] << 12) | (unsigned)b; }
    else {
      unsigned u = (ws[WS_PFX20] << 12) | (unsigned)b;
      ws[WS_THRESH] = __float_as_uint(unkey(u));
    }
  }
}

// Fused pass: provisional output write + gather bucket-b1 candidates.
// 8192 elements (2048 float4) per block; every block lies entirely inside one
// input region (sizes divide exactly), so no per-element branches.
// Wave-level shfl prefix + 2 barriers; one global atomic per block.
#define SC_E_BLKS 2048   // n0 / 8192
#define SC_M_BLKS 512    // n1 / 8192
__global__ void __launch_bounds__(256) scatter_kernel(
    const float* __restrict__ e, const float* __restrict__ m, const float* __restrict__ d,
    float* __restrict__ out, unsigned* __restrict__ ws, unsigned cap) {
  const int t = threadIdx.x;
  const int bid = blockIdx.x;
  const unsigned b1 = ws[WS_B1];

  const float4* in4;
  int out_base_v;  // vec4 index of block start within concatenated output
  if (bid < SC_E_BLKS) {
    in4 = (const float4*)e + (long long)bid * 2048;
    out_base_v = bid * 2048;
  } else if (bid < SC_E_BLKS + SC_M_BLKS) {
    in4 = (const float4*)m + (long long)(bid - SC_E_BLKS) * 2048;
    out_base_v = bid * 2048;
  } else {
    in4 = (const float4*)d + (long long)(bid - SC_E_BLKS - SC_M_BLKS) * 2048;
    out_base_v = bid * 2048;
  }
  nfloat4* out4 = (nfloat4*)out + out_base_v;

  float4 vals[8];
  unsigned c = 0;
#pragma unroll
  for (int j = 0; j < 8; ++j) {
    int v = j * 256 + t;
    float4 f = in4[v];
    vals[j] = f;
    unsigned bx = fkey(f.x) >> 24, by = fkey(f.y) >> 24;
    unsigned bz = fkey(f.z) >> 24, bw = fkey(f.w) >> 24;
    nfloat4 o;
    o.x = (bx >= b1) ? f.x : 0.0f;
    o.y = (by >= b1) ? f.y : 0.0f;
    o.z = (bz >= b1) ? f.z : 0.0f;
    o.w = (bw >= b1) ? f.w : 0.0f;
    __builtin_nontemporal_store(o, &out4[v]);
    c += (bx == b1) + (by == b1) + (bz == b1) + (bw == b1);
  }

  // wave-level inclusive prefix of c (64 lanes, shfl; no barriers)
  const int lane = t & 63;
  const int wid = t >> 6;
  unsigned p = c;
#pragma unroll
  for (int off = 1; off < 64; off <<= 1) {
    unsigned y = __shfl_up(p, off);
    if (lane >= off) p += y;
  }
  const unsigned excl = p - c;
  __shared__ unsigned wsum[4];
  __shared__ unsigned wbase[4];
  if (lane == 63) wsum[wid] = p;  // wave total
  __syncthreads();
  if (t == 0) {
    unsigned tot = wsum[0] + wsum[1] + wsum[2] + wsum[3];
    unsigned base = tot ? atomicAdd(&ws[WS_CANDCNT], tot) : 0u;
    if (base + tot > cap) atomicOr(&ws[WS_OVF], 1u);
    unsigned run = base;
    wbase[0] = run; run += wsum[0];
    wbase[1] = run; run += wsum[1];
    wbase[2] = run; run += wsum[2];
    wbase[3] = run;
  }
  __syncthreads();
  if (c) {
    unsigned slot = wbase[wid] + excl;
    float* candV = (float*)(ws + WS_CAND);
    unsigned* candI = ws + WS_CAND + cap;
#pragma unroll
    for (int j = 0; j < 8; ++j) {
      float ff[4] = {vals[j].x, vals[j].y, vals[j].z, vals[j].w};
#pragma unroll
      for (int cc = 0; cc < 4; ++cc) {
        if ((fkey(ff[cc]) >> 24) == b1) {
          if (slot < cap) {
            candV[slot] = ff[cc];
            candI[slot] = (unsigned)(out_base_v + j * 256 + t) * 4u + cc;
          }
          slot++;
        }
      }
    }
  }
}

// Stage-2/3 histograms over gathered candidates (fast) or full rescan (overflow fallback).
__global__ void cand_hist_kernel(const float* __restrict__ e, const float* __restrict__ m,
                                 const float* __restrict__ d, long long n0, long long n01,
                                 long long n, unsigned* __restrict__ ws, unsigned cap, int stage) {
  __shared__ unsigned h[4096];
  for (int i = threadIdx.x; i < 4096; i += blockDim.x) h[i] = 0u;
  __syncthreads();
  long long gtid = (long long)blockIdx.x * blockDim.x + threadIdx.x;
  long long stride = (long long)gridDim.x * blockDim.x;
  if (!ws[WS_OVF]) {
    const unsigned cnt = ws[WS_CANDCNT];
    const float* candV = (const float*)(ws + WS_CAND);
    if (stage == 2) {
      for (long long i = gtid; i < cnt; i += stride) {
        unsigned u = fkey(candV[i]);
        atomicAdd(&h[(u >> 12) & 0xFFFu], 1u);
      }
    } else {
      const unsigned pfx = ws[WS_PFX20];
      for (long long i = gtid; i < cnt; i += stride) {
        unsigned u = fkey(candV[i]);
        if ((u >> 12) == pfx) atomicAdd(&h[u & 0xFFFu], 1u);
      }
    }
  } else {
    const unsigned b1 = ws[WS_B1];
    const unsigned pfx = ws[WS_PFX20];
    for (long long i = gtid; i < n; i += stride) {
      const float* p; long long off;
      if (i < n0)       { p = e; off = i; }
      else if (i < n01) { p = m; off = i - n0; }
      else              { p = d; off = i - n01; }
      unsigned u = fkey(p[off]);
      if (stage == 2) { if ((u >> 24) == b1) atomicAdd(&h[(u >> 12) & 0xFFFu], 1u); }
      else            { if ((u >> 12) == pfx) atomicAdd(&h[u & 0xFFFu], 1u); }
    }
  }
  __syncthreads();
  unsigned* gh = ws + (stage == 2 ? WS_HIST2 : WS_HIST3);
  for (int i = threadIdx.x; i < 4096; i += blockDim.x) {
    unsigned cc = h[i];
    if (cc) atomicAdd(&gh[i], cc);
  }
}

// Zero the provisionally-kept candidates that are below the exact threshold.
__global__ void fixup_kernel(const float* __restrict__ e, const float* __restrict__ m,
                             const float* __restrict__ d, float* __restrict__ out,
                             long long n0, long long n01, long long n,
                             unsigned* __restrict__ ws, unsigned cap) {
  const float thresh = __uint_as_float(ws[WS_THRESH]);
  long long gtid = (long long)blockIdx.x * blockDim.x + threadIdx.x;
  long long stride = (long long)gridDim.x * blockDim.x;
  if (!ws[WS_OVF]) {
    const unsigned cnt = ws[WS_CANDCNT];
    const float* candV = (const float*)(ws + WS_CAND);
    const unsigned* candI = ws + WS_CAND + cap;
    for (long long i = gtid; i < cnt; i += stride) {
      float f = candV[i];
      if (f < thresh) out[candI[i]] = 0.0f;
    }
  } else {
    const unsigned b1 = ws[WS_B1];
    for (long long i = gtid; i < n; i += stride) {
      const float* p; long long off;
      if (i < n0)       { p = e; off = i; }
      else if (i < n01) { p = m; off = i - n0; }
      else              { p = d; off = i - n01; }
      float f = p[off];
      if ((fkey(f) >> 24) == b1 && f < thresh) out[i] = 0.0f;
    }
  }
}

extern "C" void kernel_launch(void* const* d_in, const int* in_sizes, int n_in,
                              void* d_out, int out_size, void* d_ws, size_t ws_size,
                              hipStream_t stream) {
  const float* e = (const float*)d_in[0];
  const float* m = (const float*)d_in[1];
  const float* d = (const float*)d_in[2];
  const int* maxf = (const int*)d_in[3];
  float* out = (float*)d_out;
  unsigned* ws = (unsigned*)d_ws;

  const long long n0 = in_sizes[0], n1 = in_sizes[1], n2 = in_sizes[2];
  const long long n = n0 + n1 + n2;
  const int n0v = (int)(n0 / 4), n1v = (int)(n1 / 4), n2v = (int)(n2 / 4);

  long long capll = ((long long)(ws_size / 4) - WS_CAND) / 2;
  if (capll < 0) capll = 0;
  if (capll > n) capll = n;
  const unsigned cap = (unsigned)capll;

  zero_ws<<<(WS_CAND + 255) / 256, 256, 0, stream>>>(ws);
  hist1_kernel<<<512, 256, 0, stream>>>(e, m, d, n0v, n1v, n2v, ws);
  select_kernel<<<1, 256, 0, stream>>>(ws, maxf, n, 1);
  const int nblocks = (int)(n / 8192);  // sizes divide exactly: 2048+512+128
  scatter_kernel<<<nblocks, 256, 0, stream>>>(e, m, d, out, ws, cap);
  cand_hist_kernel<<<32, 256, 0, stream>>>(e, m, d, n0, n0 + n1, n, ws, cap, 2);
  select_kernel<<<1, 256, 0, stream>>>(ws, maxf, n, 2);
  cand_hist_kernel<<<32, 256, 0, stream>>>(e, m, d, n0, n0 + n1, n, ws, cap, 3);
  select_kernel<<<1, 256, 0, stream>>>(ws, maxf, n, 3);
  fixup_kernel<<<256, 256, 0, stream>>>(e, m, d, out, n0, n0 + n1, n, ws, cap);
}